// Round 4
// baseline (660.078 us; speedup 1.0000x reference)
//
#include <hip/hip_runtime.h>

#define HH   112
#define WW   320
#define CIN_ 128
#define TILE 8            // pixels per block; 512 threads = 8 waves, 1 pixel/wave

__device__ __forceinline__ float lrelu(float v) {
    return v >= 0.f ? v : 0.01f * v;
}

// (512, 2): 2 blocks/CU -> 4 waves/SIMD -> 128-VGPR budget. (512,4) forced
// VGPR<=64 and the unrolled load batches spilled to scratch (269 MB of
// WRITE_SIZE/dispatch in round 3).
__global__ __launch_bounds__(512, 2)
void reg3_fused(const float* __restrict__ x_in,
                const float* __restrict__ w1_0, const float* __restrict__ b1_0,
                const float* __restrict__ w1_1, const float* __restrict__ b1_1,
                const float* __restrict__ w1_2, const float* __restrict__ b1_2,
                const float* __restrict__ w2_0, const float* __restrict__ b2_0,
                const float* __restrict__ w2_1, const float* __restrict__ b2_1,
                const float* __restrict__ w2_2, const float* __restrict__ b2_2,
                const float* __restrict__ w3_0, const float* __restrict__ b3_0,
                const float* __restrict__ w3_1, const float* __restrict__ b3_1,
                const float* __restrict__ w3_2, const float* __restrict__ b3_2,
                int* __restrict__ out)
{
    __shared__ float xT[TILE][CIN_ + 1];
    __shared__ float w1s0[32][CIN_ + 1];
    __shared__ float w1s1[32][33];
    __shared__ float w1s2[16][33];
    __shared__ float b1s[80];

    const int tilesPerLine = WW / TILE;       // 40
    const int h   = blockIdx.x / tilesPerLine;
    const int w0  = (blockIdx.x % tilesPerLine) * TILE;
    const int tid = threadIdx.x;

    for (int n = tid; n < TILE * CIN_; n += 512) {
        int ww = n & 7, c = n >> 3;
        xT[ww][c] = x_in[c * (HH * WW) + h * WW + w0 + ww];
    }
    for (int n = tid; n < 32 * CIN_; n += 512)
        w1s0[n >> 7][n & 127] = w1_0[h * (32 * CIN_) + n];
    for (int n = tid; n < 32 * 32; n += 512)
        w1s1[n >> 5][n & 31] = w1_1[h * (32 * 32) + n];
    if (tid < 16 * 32)
        w1s2[tid >> 5][tid & 31] = w1_2[h * (16 * 32) + tid];
    if      (tid < 32) b1s[tid] = b1_0[h * 32 + tid];
    else if (tid < 64) b1s[tid] = b1_1[h * 32 + (tid - 32)];
    else if (tid < 80) b1s[tid] = b1_2[h * 16 + (tid - 64)];
    __syncthreads();

    const int wave = tid >> 6;                // = pixel within tile
    const int lane = tid & 63;
    const int o    = lane & 31;
    const int half = lane >> 5;
    const int o16  = lane & 15;
    const int pix  = wave;
    const float* xr = &xT[pix][0];

    // ============ stage 1 (per-line weights, LDS) — exact np order ============
    float acc = 0.f;
    #pragma unroll
    for (int i = 0; i < 64; ++i) {
        int ii = half * 64 + i;
        acc += xr[ii] * w1s0[o][ii];
    }
    acc += __shfl_xor(acc, 32);
    float y = lrelu(acc + b1s[o]);            // y[o] at lane o (dup at o+32)

    acc = 0.f;
    #pragma unroll
    for (int i = 0; i < 32; ++i)
        acc += __shfl(y, i) * w1s1[o][i];
    float y2 = lrelu(acc + b1s[32 + o]);

    acc = 0.f;
    #pragma unroll
    for (int i = 0; i < 32; ++i)
        acc += __shfl(y2, i) * w1s2[o16][i];
    float t1 = acc + b1s[64 + o16];

    // argmax over 16 (first-index tie-break, matches np.argmax)
    float bv = t1; int bi = o16;
    #pragma unroll
    for (int d = 1; d < 16; d <<= 1) {
        float ov = __shfl_xor(bv, d);
        int   oi = __shfl_xor(bi, d);
        if (ov > bv || (ov == bv && oi < bi)) { bv = ov; bi = oi; }
    }
    const int inds1 = bi;                     // uniform across wave
    const int idx1  = inds1 + 16 * h;

    // ============ stage 2 (CondMul by idx1) — exact order, full unroll ============
    const float* Wp = w2_0 + (size_t)idx1 * (CIN_ * 32);
    acc = 0.f;
    #pragma unroll
    for (int i = 0; i < 64; ++i) {
        int ii = half * 64 + i;
        acc += xr[ii] * Wp[ii * 32 + o];      // coalesced over o
    }
    acc += __shfl_xor(acc, 32);
    y = lrelu(acc + b2_0[idx1 * 32 + o]);

    Wp = w2_1 + (size_t)idx1 * (32 * 32);
    acc = 0.f;
    #pragma unroll
    for (int i = 0; i < 32; ++i)
        acc += __shfl(y, i) * Wp[i * 32 + o];
    y2 = lrelu(acc + b2_1[idx1 * 32 + o]);

    Wp = w2_2 + (size_t)idx1 * (32 * 32);
    acc = 0.f;
    #pragma unroll
    for (int i = 0; i < 32; ++i)
        acc += __shfl(y2, i) * Wp[i * 32 + o];
    float y3 = acc + b2_2[idx1 * 32 + o];

    bv = y3; bi = o;
    #pragma unroll
    for (int d = 1; d < 32; d <<= 1) {
        float ov = __shfl_xor(bv, d);
        int   oi = __shfl_xor(bi, d);
        if (ov > bv || (ov == bv && oi < bi)) { bv = ov; bi = oi; }
    }
    const int inds2  = bi;
    const int inds12 = inds1 * 16 + inds2 - 8;          // may be <0 or >255
    const int clip12 = min(max(inds12, 0), 255);
    const int idx12  = clip12 + 256 * h;

    // ============ stage 3 (CondMul by idx12) — exact order, full unroll ============
    Wp = w3_0 + (size_t)idx12 * (CIN_ * 32);
    acc = 0.f;
    #pragma unroll
    for (int i = 0; i < 64; ++i) {
        int ii = half * 64 + i;
        acc += xr[ii] * Wp[ii * 32 + o];
    }
    acc += __shfl_xor(acc, 32);
    y = lrelu(acc + b3_0[idx12 * 32 + o]);

    Wp = w3_1 + (size_t)idx12 * (32 * 32);
    acc = 0.f;
    #pragma unroll
    for (int i = 0; i < 32; ++i)
        acc += __shfl(y, i) * Wp[i * 32 + o];
    y2 = lrelu(acc + b3_1[idx12 * 32 + o]);

    Wp = w3_2 + (size_t)idx12 * (32 * 32);
    acc = 0.f;
    #pragma unroll
    for (int i = 0; i < 32; ++i)
        acc += __shfl(y2, i) * Wp[i * 32 + o];
    y3 = acc + b3_2[idx12 * 32 + o];

    bv = y3; bi = o;
    #pragma unroll
    for (int d = 1; d < 32; d <<= 1) {
        float ov = __shfl_xor(bv, d);
        int   oi = __shfl_xor(bi, d);
        if (ov > bv || (ov == bv && oi < bi)) { bv = ov; bi = oi; }
    }
    const int inds3 = bi;
    int inds123 = inds12 * 16 + inds3 - 8;
    inds123 = min(max(inds123, 0), 4095);

    if (lane == 0) out[h * WW + w0 + pix] = inds123;
}

extern "C" void kernel_launch(void* const* d_in, const int* in_sizes, int n_in,
                              void* d_out, int out_size, void* d_ws, size_t ws_size,
                              hipStream_t stream)
{
    const float* x_in = (const float*)d_in[0];
    const float* w1_0 = (const float*)d_in[1];
    const float* b1_0 = (const float*)d_in[2];
    const float* w1_1 = (const float*)d_in[3];
    const float* b1_1 = (const float*)d_in[4];
    const float* w1_2 = (const float*)d_in[5];
    const float* b1_2 = (const float*)d_in[6];
    const float* w2_0 = (const float*)d_in[7];
    const float* b2_0 = (const float*)d_in[8];
    const float* w2_1 = (const float*)d_in[9];
    const float* b2_1 = (const float*)d_in[10];
    const float* w2_2 = (const float*)d_in[11];
    const float* b2_2 = (const float*)d_in[12];
    const float* w3_0 = (const float*)d_in[13];
    const float* b3_0 = (const float*)d_in[14];
    const float* w3_1 = (const float*)d_in[15];
    const float* b3_1 = (const float*)d_in[16];
    const float* w3_2 = (const float*)d_in[17];
    const float* b3_2 = (const float*)d_in[18];
    int* out = (int*)d_out;

    dim3 grid(HH * (WW / TILE));   // 4480 blocks x 512 threads
    reg3_fused<<<grid, 512, 0, stream>>>(
        x_in, w1_0, b1_0, w1_1, b1_1, w1_2, b1_2,
        w2_0, b2_0, w2_1, b2_1, w2_2, b2_2,
        w3_0, b3_0, w3_1, b3_1, w3_2, b3_2, out);
}

// Round 5
// 511.273 us; speedup vs baseline: 1.2910x; 1.2910x over previous
//
#include <hip/hip_runtime.h>

#define HH   112
#define WW   320
#define CIN_ 128
#define HW_  (HH * WW)        // 35840

__device__ __forceinline__ float lrelu(float v) {
    return v >= 0.f ? v : 0.01f * v;
}

// ============================================================================
// K1: stage 1 (per-line grouped 1x1 chain) -> inds1, plus optional xT dump.
// 4 blocks per line, 80 pixels each (10 tiles x 8 waves x 1 pixel).
// Inner arithmetic is byte-identical to the proven round-3 kernel.
// ============================================================================
template <bool XT>
__global__ __launch_bounds__(512, 2)
void k1_stage1(const float* __restrict__ x_in,
               const float* __restrict__ w1_0, const float* __restrict__ b1_0,
               const float* __restrict__ w1_1, const float* __restrict__ b1_1,
               const float* __restrict__ w1_2, const float* __restrict__ b1_2,
               int* __restrict__ inds1_out, float* __restrict__ xT_out)
{
    __shared__ float w1s0[32][CIN_ + 1];
    __shared__ float w1s1[32][33];
    __shared__ float w1s2[16][33];
    __shared__ float b1s[80];
    __shared__ float xT[8][CIN_ + 1];

    const int h   = blockIdx.x >> 2;
    const int q   = blockIdx.x & 3;
    const int tid = threadIdx.x;

    for (int n = tid; n < 32 * CIN_; n += 512)
        w1s0[n >> 7][n & 127] = w1_0[h * (32 * CIN_) + n];
    for (int n = tid; n < 32 * 32; n += 512)
        w1s1[n >> 5][n & 31] = w1_1[h * 1024 + n];
    if (tid < 16 * 32)
        w1s2[tid >> 5][tid & 31] = w1_2[h * 512 + tid];
    if      (tid < 32) b1s[tid] = b1_0[h * 32 + tid];
    else if (tid < 64) b1s[tid] = b1_1[h * 32 + (tid - 32)];
    else if (tid < 80) b1s[tid] = b1_2[h * 16 + (tid - 64)];
    __syncthreads();

    const int wave = tid >> 6;
    const int lane = tid & 63;
    const int o    = lane & 31;
    const int half = lane >> 5;
    const int o16  = lane & 15;

    for (int t = 0; t < 10; ++t) {
        const int w0 = q * 80 + t * 8;
        for (int n = tid; n < 8 * CIN_; n += 512) {
            int ww = n & 7, c = n >> 3;
            xT[ww][c] = x_in[c * HW_ + h * WW + w0 + ww];
        }
        __syncthreads();
        if (XT) {
            for (int n = tid; n < 8 * CIN_; n += 512) {
                int pix = n >> 7, c = n & 127;
                xT_out[(size_t)(h * WW + w0 + pix) * CIN_ + c] = xT[pix][c];
            }
        }
        const float* xr = &xT[wave][0];

        float acc = 0.f;
        #pragma unroll
        for (int i = 0; i < 64; ++i) {
            int ii = half * 64 + i;
            acc += xr[ii] * w1s0[o][ii];
        }
        acc += __shfl_xor(acc, 32);
        float y = lrelu(acc + b1s[o]);

        acc = 0.f;
        #pragma unroll
        for (int i = 0; i < 32; ++i)
            acc += __shfl(y, i) * w1s1[o][i];
        float y2 = lrelu(acc + b1s[32 + o]);

        acc = 0.f;
        #pragma unroll
        for (int i = 0; i < 32; ++i)
            acc += __shfl(y2, i) * w1s2[o16][i];
        float t1 = acc + b1s[64 + o16];

        float bv = t1; int bi = o16;
        #pragma unroll
        for (int d = 1; d < 16; d <<= 1) {
            float ov = __shfl_xor(bv, d);
            int   oi = __shfl_xor(bi, d);
            if (ov > bv || (ov == bv && oi < bi)) { bv = ov; bi = oi; }
        }
        if (lane == 0) inds1_out[h * WW + w0 + wave] = bi;
        __syncthreads();
    }
}

// ============================================================================
// K2: stage 2, condition-centric. Block = (line h, class c in 0..15).
// Scan line's inds1; if any pixel routed here, stream w2 chain into LDS
// once (coalesced) and process matched pixels, 1 pixel per wave.
// ============================================================================
template <bool XT>
__global__ __launch_bounds__(512, 2)
void k2_stage2(const float* __restrict__ x_in, const float* __restrict__ xT_in,
               const int* __restrict__ inds1_in,
               const float* __restrict__ w2_0, const float* __restrict__ b2_0,
               const float* __restrict__ w2_1, const float* __restrict__ b2_1,
               const float* __restrict__ w2_2, const float* __restrict__ b2_2,
               int* __restrict__ inds12_out)
{
    __shared__ float ws0[CIN_ * 32];
    __shared__ float ws1[32 * 32];
    __shared__ float ws2[32 * 32];
    __shared__ float bs[96];
    __shared__ float xbuf[8][CIN_];
    __shared__ int   list[WW];
    __shared__ int   cnt;

    const int h   = blockIdx.x >> 4;
    const int c   = blockIdx.x & 15;
    const int tid = threadIdx.x;
    const int base = h * WW;

    if (tid == 0) cnt = 0;
    __syncthreads();
    if (tid < WW) {
        if (inds1_in[base + tid] == c) {
            int p = atomicAdd(&cnt, 1);
            list[p] = tid;
        }
    }
    __syncthreads();
    const int n = cnt;
    if (n == 0) return;

    const int idx1 = h * 16 + c;
    for (int i = tid; i < 1024; i += 512)
        ((float4*)ws0)[i] = ((const float4*)(w2_0 + (size_t)idx1 * 4096))[i];
    if (tid < 256)
        ((float4*)ws1)[tid] = ((const float4*)(w2_1 + (size_t)idx1 * 1024))[tid];
    else
        ((float4*)ws2)[tid - 256] = ((const float4*)(w2_2 + (size_t)idx1 * 1024))[tid - 256];
    if      (tid < 32) bs[tid]      = b2_0[(size_t)idx1 * 32 + tid];
    else if (tid < 64) bs[tid]      = b2_1[(size_t)idx1 * 32 + (tid - 32)];
    else if (tid < 96) bs[tid]      = b2_2[(size_t)idx1 * 32 + (tid - 64)];
    __syncthreads();

    const int wave = tid >> 6;
    const int lane = tid & 63;
    const int o    = lane & 31;
    const int half = lane >> 5;

    for (int it = wave; it < n; it += 8) {
        const int pix = base + list[it];
        if (XT) {
            xbuf[wave][lane]      = xT_in[(size_t)pix * CIN_ + lane];
            xbuf[wave][64 + lane] = xT_in[(size_t)pix * CIN_ + 64 + lane];
        } else {
            xbuf[wave][lane]      = x_in[(size_t)lane * HW_ + pix];
            xbuf[wave][64 + lane] = x_in[(size_t)(64 + lane) * HW_ + pix];
        }
        asm volatile("s_waitcnt vmcnt(0) lgkmcnt(0)" ::: "memory");
        const float* xr = &xbuf[wave][0];

        float acc = 0.f;
        #pragma unroll
        for (int i = 0; i < 64; ++i) {
            int ii = half * 64 + i;
            acc += xr[ii] * ws0[ii * 32 + o];
        }
        acc += __shfl_xor(acc, 32);
        float y = lrelu(acc + bs[o]);

        acc = 0.f;
        #pragma unroll
        for (int i = 0; i < 32; ++i)
            acc += __shfl(y, i) * ws1[i * 32 + o];
        float y2 = lrelu(acc + bs[32 + o]);

        acc = 0.f;
        #pragma unroll
        for (int i = 0; i < 32; ++i)
            acc += __shfl(y2, i) * ws2[i * 32 + o];
        float y3 = acc + bs[64 + o];

        float bv = y3; int bi = o;
        #pragma unroll
        for (int d = 1; d < 32; d <<= 1) {
            float ov = __shfl_xor(bv, d);
            int   oi = __shfl_xor(bi, d);
            if (ov > bv || (ov == bv && oi < bi)) { bv = ov; bi = oi; }
        }
        if (lane == 0) inds12_out[pix] = c * 16 + bi - 8;   // unclipped
    }
}

// ============================================================================
// K3: stage 3, condition-centric. Block = (line h, clipped inds12 c in 0..255).
// Most blocks have no matching pixel and exit after a 1.25 KB scan.
// ============================================================================
template <bool XT>
__global__ __launch_bounds__(512, 2)
void k3_stage3(const float* __restrict__ x_in, const float* __restrict__ xT_in,
               const int* __restrict__ inds12_in,
               const float* __restrict__ w3_0, const float* __restrict__ b3_0,
               const float* __restrict__ w3_1, const float* __restrict__ b3_1,
               const float* __restrict__ w3_2, const float* __restrict__ b3_2,
               int* __restrict__ out)
{
    __shared__ float ws0[CIN_ * 32];
    __shared__ float ws1[32 * 32];
    __shared__ float ws2[32 * 32];
    __shared__ float bs[96];
    __shared__ float xbuf[8][CIN_];
    __shared__ int   list[WW];
    __shared__ int   cnt;

    const int h   = blockIdx.x >> 8;
    const int c   = blockIdx.x & 255;
    const int tid = threadIdx.x;
    const int base = h * WW;

    if (tid == 0) cnt = 0;
    __syncthreads();
    if (tid < WW) {
        int v = inds12_in[base + tid];
        int cl = min(max(v, 0), 255);
        if (cl == c) {
            int p = atomicAdd(&cnt, 1);
            list[p] = tid;
        }
    }
    __syncthreads();
    const int n = cnt;
    if (n == 0) return;

    const int idx12 = h * 256 + c;
    for (int i = tid; i < 1024; i += 512)
        ((float4*)ws0)[i] = ((const float4*)(w3_0 + (size_t)idx12 * 4096))[i];
    if (tid < 256)
        ((float4*)ws1)[tid] = ((const float4*)(w3_1 + (size_t)idx12 * 1024))[tid];
    else
        ((float4*)ws2)[tid - 256] = ((const float4*)(w3_2 + (size_t)idx12 * 1024))[tid - 256];
    if      (tid < 32) bs[tid]      = b3_0[(size_t)idx12 * 32 + tid];
    else if (tid < 64) bs[tid]      = b3_1[(size_t)idx12 * 32 + (tid - 32)];
    else if (tid < 96) bs[tid]      = b3_2[(size_t)idx12 * 32 + (tid - 64)];
    __syncthreads();

    const int wave = tid >> 6;
    const int lane = tid & 63;
    const int o    = lane & 31;
    const int half = lane >> 5;

    for (int it = wave; it < n; it += 8) {
        const int pix = base + list[it];
        if (XT) {
            xbuf[wave][lane]      = xT_in[(size_t)pix * CIN_ + lane];
            xbuf[wave][64 + lane] = xT_in[(size_t)pix * CIN_ + 64 + lane];
        } else {
            xbuf[wave][lane]      = x_in[(size_t)lane * HW_ + pix];
            xbuf[wave][64 + lane] = x_in[(size_t)(64 + lane) * HW_ + pix];
        }
        asm volatile("s_waitcnt vmcnt(0) lgkmcnt(0)" ::: "memory");
        const float* xr = &xbuf[wave][0];

        float acc = 0.f;
        #pragma unroll
        for (int i = 0; i < 64; ++i) {
            int ii = half * 64 + i;
            acc += xr[ii] * ws0[ii * 32 + o];
        }
        acc += __shfl_xor(acc, 32);
        float y = lrelu(acc + bs[o]);

        acc = 0.f;
        #pragma unroll
        for (int i = 0; i < 32; ++i)
            acc += __shfl(y, i) * ws1[i * 32 + o];
        float y2 = lrelu(acc + bs[32 + o]);

        acc = 0.f;
        #pragma unroll
        for (int i = 0; i < 32; ++i)
            acc += __shfl(y2, i) * ws2[i * 32 + o];
        float y3 = acc + bs[64 + o];

        float bv = y3; int bi = o;
        #pragma unroll
        for (int d = 1; d < 32; d <<= 1) {
            float ov = __shfl_xor(bv, d);
            int   oi = __shfl_xor(bi, d);
            if (ov > bv || (ov == bv && oi < bi)) { bv = ov; bi = oi; }
        }
        if (lane == 0) {
            int v12 = inds12_in[pix];                       // unclipped
            out[pix] = min(max(v12 * 16 + bi - 8, 0), 4095);
        }
    }
}

// ============================================================================
// Fallback: proven round-3 monolithic kernel (used only if d_ws too small).
// ============================================================================
__global__ __launch_bounds__(512, 4)
void reg3_fused(const float* __restrict__ x_in,
                const float* __restrict__ w1_0, const float* __restrict__ b1_0,
                const float* __restrict__ w1_1, const float* __restrict__ b1_1,
                const float* __restrict__ w1_2, const float* __restrict__ b1_2,
                const float* __restrict__ w2_0, const float* __restrict__ b2_0,
                const float* __restrict__ w2_1, const float* __restrict__ b2_1,
                const float* __restrict__ w2_2, const float* __restrict__ b2_2,
                const float* __restrict__ w3_0, const float* __restrict__ b3_0,
                const float* __restrict__ w3_1, const float* __restrict__ b3_1,
                const float* __restrict__ w3_2, const float* __restrict__ b3_2,
                int* __restrict__ out)
{
    __shared__ float xT[8][CIN_ + 1];
    __shared__ float w1s0[32][CIN_ + 1];
    __shared__ float w1s1[32][33];
    __shared__ float w1s2[16][33];
    __shared__ float b1s[80];

    const int h   = blockIdx.x / 40;
    const int w0  = (blockIdx.x % 40) * 8;
    const int tid = threadIdx.x;

    for (int n = tid; n < 8 * CIN_; n += 512) {
        int ww = n & 7, c = n >> 3;
        xT[ww][c] = x_in[c * HW_ + h * WW + w0 + ww];
    }
    for (int n = tid; n < 32 * CIN_; n += 512)
        w1s0[n >> 7][n & 127] = w1_0[h * (32 * CIN_) + n];
    for (int n = tid; n < 32 * 32; n += 512)
        w1s1[n >> 5][n & 31] = w1_1[h * 1024 + n];
    if (tid < 16 * 32)
        w1s2[tid >> 5][tid & 31] = w1_2[h * 512 + tid];
    if      (tid < 32) b1s[tid] = b1_0[h * 32 + tid];
    else if (tid < 64) b1s[tid] = b1_1[h * 32 + (tid - 32)];
    else if (tid < 80) b1s[tid] = b1_2[h * 16 + (tid - 64)];
    __syncthreads();

    const int wave = tid >> 6, lane = tid & 63;
    const int o = lane & 31, half = lane >> 5, o16 = lane & 15;
    const float* xr = &xT[wave][0];

    float acc = 0.f;
    #pragma unroll
    for (int i = 0; i < 64; ++i) { int ii = half * 64 + i; acc += xr[ii] * w1s0[o][ii]; }
    acc += __shfl_xor(acc, 32);
    float y = lrelu(acc + b1s[o]);
    acc = 0.f;
    #pragma unroll
    for (int i = 0; i < 32; ++i) acc += __shfl(y, i) * w1s1[o][i];
    float y2 = lrelu(acc + b1s[32 + o]);
    acc = 0.f;
    #pragma unroll
    for (int i = 0; i < 32; ++i) acc += __shfl(y2, i) * w1s2[o16][i];
    float t1 = acc + b1s[64 + o16];

    float bv = t1; int bi = o16;
    #pragma unroll
    for (int d = 1; d < 16; d <<= 1) {
        float ov = __shfl_xor(bv, d); int oi = __shfl_xor(bi, d);
        if (ov > bv || (ov == bv && oi < bi)) { bv = ov; bi = oi; }
    }
    const int inds1 = bi;
    const int idx1  = inds1 + 16 * h;

    const float* Wp = w2_0 + (size_t)idx1 * (CIN_ * 32);
    acc = 0.f;
    #pragma unroll
    for (int i = 0; i < 64; ++i) { int ii = half * 64 + i; acc += xr[ii] * Wp[ii * 32 + o]; }
    acc += __shfl_xor(acc, 32);
    y = lrelu(acc + b2_0[idx1 * 32 + o]);
    Wp = w2_1 + (size_t)idx1 * 1024;
    acc = 0.f;
    #pragma unroll
    for (int i = 0; i < 32; ++i) acc += __shfl(y, i) * Wp[i * 32 + o];
    y2 = lrelu(acc + b2_1[idx1 * 32 + o]);
    Wp = w2_2 + (size_t)idx1 * 1024;
    acc = 0.f;
    #pragma unroll
    for (int i = 0; i < 32; ++i) acc += __shfl(y2, i) * Wp[i * 32 + o];
    float y3 = acc + b2_2[idx1 * 32 + o];

    bv = y3; bi = o;
    #pragma unroll
    for (int d = 1; d < 32; d <<= 1) {
        float ov = __shfl_xor(bv, d); int oi = __shfl_xor(bi, d);
        if (ov > bv || (ov == bv && oi < bi)) { bv = ov; bi = oi; }
    }
    const int inds2  = bi;
    const int inds12 = inds1 * 16 + inds2 - 8;
    const int clip12 = min(max(inds12, 0), 255);
    const int idx12  = clip12 + 256 * h;

    Wp = w3_0 + (size_t)idx12 * (CIN_ * 32);
    acc = 0.f;
    #pragma unroll
    for (int i = 0; i < 64; ++i) { int ii = half * 64 + i; acc += xr[ii] * Wp[ii * 32 + o]; }
    acc += __shfl_xor(acc, 32);
    y = lrelu(acc + b3_0[idx12 * 32 + o]);
    Wp = w3_1 + (size_t)idx12 * 1024;
    acc = 0.f;
    #pragma unroll
    for (int i = 0; i < 32; ++i) acc += __shfl(y, i) * Wp[i * 32 + o];
    y2 = lrelu(acc + b3_1[idx12 * 32 + o]);
    Wp = w3_2 + (size_t)idx12 * 1024;
    acc = 0.f;
    #pragma unroll
    for (int i = 0; i < 32; ++i) acc += __shfl(y2, i) * Wp[i * 32 + o];
    y3 = acc + b3_2[idx12 * 32 + o];

    bv = y3; bi = o;
    #pragma unroll
    for (int d = 1; d < 32; d <<= 1) {
        float ov = __shfl_xor(bv, d); int oi = __shfl_xor(bi, d);
        if (ov > bv || (ov == bv && oi < bi)) { bv = ov; bi = oi; }
    }
    int inds123 = inds12 * 16 + bi - 8;
    inds123 = min(max(inds123, 0), 4095);
    if (lane == 0) out[h * WW + w0 + wave] = inds123;
}

extern "C" void kernel_launch(void* const* d_in, const int* in_sizes, int n_in,
                              void* d_out, int out_size, void* d_ws, size_t ws_size,
                              hipStream_t stream)
{
    const float* x_in = (const float*)d_in[0];
    const float* w1_0 = (const float*)d_in[1];
    const float* b1_0 = (const float*)d_in[2];
    const float* w1_1 = (const float*)d_in[3];
    const float* b1_1 = (const float*)d_in[4];
    const float* w1_2 = (const float*)d_in[5];
    const float* b1_2 = (const float*)d_in[6];
    const float* w2_0 = (const float*)d_in[7];
    const float* b2_0 = (const float*)d_in[8];
    const float* w2_1 = (const float*)d_in[9];
    const float* b2_1 = (const float*)d_in[10];
    const float* w2_2 = (const float*)d_in[11];
    const float* b2_2 = (const float*)d_in[12];
    const float* w3_0 = (const float*)d_in[13];
    const float* b3_0 = (const float*)d_in[14];
    const float* w3_1 = (const float*)d_in[15];
    const float* b3_1 = (const float*)d_in[16];
    const float* w3_2 = (const float*)d_in[17];
    const float* b3_2 = (const float*)d_in[18];
    int* out = (int*)d_out;

    int*   inds1_ws  = (int*)d_ws;
    int*   inds12_ws = (int*)((char*)d_ws + (size_t)HW_ * 4);
    float* xT_ws     = (float*)((char*)d_ws + (size_t)HW_ * 8);
    const size_t NEED_MIN = (size_t)HW_ * 8;                       // 286,720 B
    const size_t NEED_XT  = NEED_MIN + (size_t)HW_ * CIN_ * 4;     // + 18.35 MB

    if (ws_size >= NEED_XT) {
        k1_stage1<true><<<HH * 4, 512, 0, stream>>>(
            x_in, w1_0, b1_0, w1_1, b1_1, w1_2, b1_2, inds1_ws, xT_ws);
        k2_stage2<true><<<HH * 16, 512, 0, stream>>>(
            x_in, xT_ws, inds1_ws, w2_0, b2_0, w2_1, b2_1, w2_2, b2_2, inds12_ws);
        k3_stage3<true><<<HH * 256, 512, 0, stream>>>(
            x_in, xT_ws, inds12_ws, w3_0, b3_0, w3_1, b3_1, w3_2, b3_2, out);
    } else if (ws_size >= NEED_MIN) {
        k1_stage1<false><<<HH * 4, 512, 0, stream>>>(
            x_in, w1_0, b1_0, w1_1, b1_1, w1_2, b1_2, inds1_ws, nullptr);
        k2_stage2<false><<<HH * 16, 512, 0, stream>>>(
            x_in, nullptr, inds1_ws, w2_0, b2_0, w2_1, b2_1, w2_2, b2_2, inds12_ws);
        k3_stage3<false><<<HH * 256, 512, 0, stream>>>(
            x_in, nullptr, inds12_ws, w3_0, b3_0, w3_1, b3_1, w3_2, b3_2, out);
    } else {
        reg3_fused<<<HH * 40, 512, 0, stream>>>(
            x_in, w1_0, b1_0, w1_1, b1_1, w1_2, b1_2,
            w2_0, b2_0, w2_1, b2_1, w2_2, b2_2,
            w3_0, b3_0, w3_1, b3_1, w3_2, b3_2, out);
    }
}

// Round 6
// 281.353 us; speedup vs baseline: 2.3461x; 1.8172x over previous
//
#include <hip/hip_runtime.h>

#define HH   112
#define WW   320
#define CIN_ 128
#define HW_  (HH * WW)        // 35840
#define CHUNK 32              // max pixels per queue item (<=4 rounds of 8 waves)

__device__ __forceinline__ float lrelu(float v) {
    return v >= 0.f ? v : 0.01f * v;
}

// ============================================================================
// K1: stage 1 (per-line grouped 1x1 chain) -> inds1 + xT dump; zeroes qcounts.
// 4 blocks per line, 80 pixels each (10 tiles x 8 waves x 1 pixel).
// Inner arithmetic byte-identical to the proven bit-exact kernel.
// ============================================================================
__global__ __launch_bounds__(512, 2)
void k1_stage1(const float* __restrict__ x_in,
               const float* __restrict__ w1_0, const float* __restrict__ b1_0,
               const float* __restrict__ w1_1, const float* __restrict__ b1_1,
               const float* __restrict__ w1_2, const float* __restrict__ b1_2,
               int* __restrict__ inds1_out, float* __restrict__ xT_out,
               int* __restrict__ qc2, int* __restrict__ qc3)
{
    __shared__ float w1s0[32][CIN_ + 1];
    __shared__ float w1s1[32][33];
    __shared__ float w1s2[16][33];
    __shared__ float b1s[80];
    __shared__ float xT[8][CIN_ + 1];

    const int h   = blockIdx.x >> 2;
    const int q   = blockIdx.x & 3;
    const int tid = threadIdx.x;

    if (blockIdx.x == 0 && tid == 0) { *qc2 = 0; *qc3 = 0; }

    for (int n = tid; n < 32 * CIN_; n += 512)
        w1s0[n >> 7][n & 127] = w1_0[h * (32 * CIN_) + n];
    for (int n = tid; n < 32 * 32; n += 512)
        w1s1[n >> 5][n & 31] = w1_1[h * 1024 + n];
    if (tid < 16 * 32)
        w1s2[tid >> 5][tid & 31] = w1_2[h * 512 + tid];
    if      (tid < 32) b1s[tid] = b1_0[h * 32 + tid];
    else if (tid < 64) b1s[tid] = b1_1[h * 32 + (tid - 32)];
    else if (tid < 80) b1s[tid] = b1_2[h * 16 + (tid - 64)];
    __syncthreads();

    const int wave = tid >> 6;
    const int lane = tid & 63;
    const int o    = lane & 31;
    const int half = lane >> 5;
    const int o16  = lane & 15;

    for (int t = 0; t < 10; ++t) {
        const int w0 = q * 80 + t * 8;
        for (int n = tid; n < 8 * CIN_; n += 512) {
            int ww = n & 7, c = n >> 3;
            xT[ww][c] = x_in[c * HW_ + h * WW + w0 + ww];
        }
        __syncthreads();
        for (int n = tid; n < 8 * CIN_; n += 512) {
            int pix = n >> 7, c = n & 127;
            xT_out[(size_t)(h * WW + w0 + pix) * CIN_ + c] = xT[pix][c];
        }
        const float* xr = &xT[wave][0];

        float acc = 0.f;
        #pragma unroll
        for (int i = 0; i < 64; ++i) {
            int ii = half * 64 + i;
            acc += xr[ii] * w1s0[o][ii];
        }
        acc += __shfl_xor(acc, 32);
        float y = lrelu(acc + b1s[o]);

        acc = 0.f;
        #pragma unroll
        for (int i = 0; i < 32; ++i)
            acc += __shfl(y, i) * w1s1[o][i];
        float y2 = lrelu(acc + b1s[32 + o]);

        acc = 0.f;
        #pragma unroll
        for (int i = 0; i < 32; ++i)
            acc += __shfl(y2, i) * w1s2[o16][i];
        float t1 = acc + b1s[64 + o16];

        float bv = t1; int bi = o16;
        #pragma unroll
        for (int d = 1; d < 16; d <<= 1) {
            float ov = __shfl_xor(bv, d);
            int   oi = __shfl_xor(bi, d);
            if (ov > bv || (ov == bv && oi < bi)) { bv = ov; bi = oi; }
        }
        if (lane == 0) inds1_out[h * WW + w0 + wave] = bi;
        __syncthreads();
    }
}

// ============================================================================
// Sorter: one block per line. Bucket-sort the line's pixels by (clipped)
// routing index, emit <=CHUNK-pixel work items {h, c, start, count} to queue.
// Item order is nondeterministic (atomics) but the item SET and all final
// outputs are deterministic.
// ============================================================================
template <int BINS>
__global__ void sorter(const int* __restrict__ inds_in, int clipmax,
                       int* __restrict__ sorted, int4* __restrict__ queue,
                       int* __restrict__ qcount)
{
    __shared__ int cnt[BINS];
    __shared__ int scan[BINS];
    __shared__ int rank[BINS];

    const int h = blockIdx.x, tid = threadIdx.x, base = h * WW;
    if (tid < BINS) { cnt[tid] = 0; rank[tid] = 0; }
    __syncthreads();

    int c = -1;
    if (tid < WW) {
        c = inds_in[base + tid];
        c = min(max(c, 0), clipmax);
        atomicAdd(&cnt[c], 1);
    }
    __syncthreads();
    if (tid < BINS) scan[tid] = cnt[tid];
    __syncthreads();
    for (int s = 1; s < BINS; s <<= 1) {
        int v = 0;
        if (tid >= s && tid < BINS) v = scan[tid - s];
        __syncthreads();
        if (tid < BINS) scan[tid] += v;
        __syncthreads();
    }
    // scan = inclusive prefix; exclusive offset = scan - cnt
    if (tid < WW) {
        int pos = (scan[c] - cnt[c]) + atomicAdd(&rank[c], 1);
        sorted[base + pos] = base + tid;          // absolute pixel id
    }
    if (tid < BINS && cnt[tid] > 0) {
        int offc = scan[tid] - cnt[tid];
        for (int s0 = 0; s0 < cnt[tid]; s0 += CHUNK) {
            int qi = atomicAdd(qcount, 1);
            queue[qi] = make_int4(h, tid, base + offc + s0,
                                  min(CHUNK, cnt[tid] - s0));
        }
    }
}

// ============================================================================
// Queue-driven CondMul chain. Fixed grid, grid-stride over qcount items.
// Per item: stage 24.6 KB weight chain into LDS once, process <=CHUNK pixels
// in <=4 rounds of 8 waves. Inner arithmetic byte-identical to proven code.
// STAGE==2: result[pix] = c*16 + argmax - 8 (unclipped inds12)
// STAGE==3: result[pix] = clip(inds12[pix]*16 + argmax - 8, 0, 4095)
// ============================================================================
template <int STAGE>
__global__ __launch_bounds__(512, 2)
void qk_compute(const float* __restrict__ xT_in, const int* __restrict__ sorted,
                const int4* __restrict__ queue, const int* __restrict__ qcount,
                const float* __restrict__ W0, const float* __restrict__ Bb0,
                const float* __restrict__ W1, const float* __restrict__ Bb1,
                const float* __restrict__ W2, const float* __restrict__ Bb2,
                const int* __restrict__ inds12_in, int* __restrict__ result)
{
    __shared__ float ws0[CIN_ * 32];
    __shared__ float ws1[32 * 32];
    __shared__ float ws2[32 * 32];
    __shared__ float bs[96];
    __shared__ float xbuf[8][CIN_];

    const int tid  = threadIdx.x;
    const int wave = tid >> 6;
    const int lane = tid & 63;
    const int o    = lane & 31;
    const int half = lane >> 5;

    const int qn = *qcount;
    for (int qi = blockIdx.x; qi < qn; qi += gridDim.x) {
        const int4 it4  = queue[qi];
        const int  c    = it4.y;
        const int  start = it4.z;
        const int  n    = it4.w;
        const int  key  = (STAGE == 2) ? (it4.x * 16 + c) : (it4.x * 256 + c);

        __syncthreads();                          // protect LDS reuse
        for (int i = tid; i < 1024; i += 512)
            ((float4*)ws0)[i] = ((const float4*)(W0 + (size_t)key * 4096))[i];
        if (tid < 256)
            ((float4*)ws1)[tid] = ((const float4*)(W1 + (size_t)key * 1024))[tid];
        else if (tid < 512)
            ((float4*)ws2)[tid - 256] = ((const float4*)(W2 + (size_t)key * 1024))[tid - 256];
        if      (tid < 32) bs[tid] = Bb0[(size_t)key * 32 + tid];
        else if (tid < 64) bs[tid] = Bb1[(size_t)key * 32 + (tid - 32)];
        else if (tid < 96) bs[tid] = Bb2[(size_t)key * 32 + (tid - 64)];
        __syncthreads();

        for (int t = wave; t < n; t += 8) {
            const int pix = sorted[start + t];
            xbuf[wave][lane]      = xT_in[(size_t)pix * CIN_ + lane];
            xbuf[wave][64 + lane] = xT_in[(size_t)pix * CIN_ + 64 + lane];
            asm volatile("s_waitcnt vmcnt(0) lgkmcnt(0)" ::: "memory");
            const float* xr = &xbuf[wave][0];

            float acc = 0.f;
            #pragma unroll
            for (int i = 0; i < 64; ++i) {
                int ii = half * 64 + i;
                acc += xr[ii] * ws0[ii * 32 + o];
            }
            acc += __shfl_xor(acc, 32);
            float y = lrelu(acc + bs[o]);

            acc = 0.f;
            #pragma unroll
            for (int i = 0; i < 32; ++i)
                acc += __shfl(y, i) * ws1[i * 32 + o];
            float y2 = lrelu(acc + bs[32 + o]);

            acc = 0.f;
            #pragma unroll
            for (int i = 0; i < 32; ++i)
                acc += __shfl(y2, i) * ws2[i * 32 + o];
            float y3 = acc + bs[64 + o];

            float bv = y3; int bi = o;
            #pragma unroll
            for (int d = 1; d < 32; d <<= 1) {
                float ov = __shfl_xor(bv, d);
                int   oi = __shfl_xor(bi, d);
                if (ov > bv || (ov == bv && oi < bi)) { bv = ov; bi = oi; }
            }
            if (lane == 0) {
                if (STAGE == 2) {
                    result[pix] = c * 16 + bi - 8;              // unclipped
                } else {
                    int v12 = inds12_in[pix];                   // unclipped
                    result[pix] = min(max(v12 * 16 + bi - 8, 0), 4095);
                }
            }
        }
    }
}

// ============================================================================
// Fallback: proven monolithic kernel (only if d_ws too small — not expected).
// ============================================================================
__global__ __launch_bounds__(512, 4)
void reg3_fused(const float* __restrict__ x_in,
                const float* __restrict__ w1_0, const float* __restrict__ b1_0,
                const float* __restrict__ w1_1, const float* __restrict__ b1_1,
                const float* __restrict__ w1_2, const float* __restrict__ b1_2,
                const float* __restrict__ w2_0, const float* __restrict__ b2_0,
                const float* __restrict__ w2_1, const float* __restrict__ b2_1,
                const float* __restrict__ w2_2, const float* __restrict__ b2_2,
                const float* __restrict__ w3_0, const float* __restrict__ b3_0,
                const float* __restrict__ w3_1, const float* __restrict__ b3_1,
                const float* __restrict__ w3_2, const float* __restrict__ b3_2,
                int* __restrict__ out)
{
    __shared__ float xT[8][CIN_ + 1];
    __shared__ float w1s0[32][CIN_ + 1];
    __shared__ float w1s1[32][33];
    __shared__ float w1s2[16][33];
    __shared__ float b1s[80];

    const int h   = blockIdx.x / 40;
    const int w0  = (blockIdx.x % 40) * 8;
    const int tid = threadIdx.x;

    for (int n = tid; n < 8 * CIN_; n += 512) {
        int ww = n & 7, c = n >> 3;
        xT[ww][c] = x_in[c * HW_ + h * WW + w0 + ww];
    }
    for (int n = tid; n < 32 * CIN_; n += 512)
        w1s0[n >> 7][n & 127] = w1_0[h * (32 * CIN_) + n];
    for (int n = tid; n < 32 * 32; n += 512)
        w1s1[n >> 5][n & 31] = w1_1[h * 1024 + n];
    if (tid < 16 * 32)
        w1s2[tid >> 5][tid & 31] = w1_2[h * 512 + tid];
    if      (tid < 32) b1s[tid] = b1_0[h * 32 + tid];
    else if (tid < 64) b1s[tid] = b1_1[h * 32 + (tid - 32)];
    else if (tid < 80) b1s[tid] = b1_2[h * 16 + (tid - 64)];
    __syncthreads();

    const int wave = tid >> 6, lane = tid & 63;
    const int o = lane & 31, half = lane >> 5, o16 = lane & 15;
    const float* xr = &xT[wave][0];

    float acc = 0.f;
    #pragma unroll
    for (int i = 0; i < 64; ++i) { int ii = half * 64 + i; acc += xr[ii] * w1s0[o][ii]; }
    acc += __shfl_xor(acc, 32);
    float y = lrelu(acc + b1s[o]);
    acc = 0.f;
    #pragma unroll
    for (int i = 0; i < 32; ++i) acc += __shfl(y, i) * w1s1[o][i];
    float y2 = lrelu(acc + b1s[32 + o]);
    acc = 0.f;
    #pragma unroll
    for (int i = 0; i < 32; ++i) acc += __shfl(y2, i) * w1s2[o16][i];
    float t1 = acc + b1s[64 + o16];

    float bv = t1; int bi = o16;
    #pragma unroll
    for (int d = 1; d < 16; d <<= 1) {
        float ov = __shfl_xor(bv, d); int oi = __shfl_xor(bi, d);
        if (ov > bv || (ov == bv && oi < bi)) { bv = ov; bi = oi; }
    }
    const int inds1 = bi;
    const int idx1  = inds1 + 16 * h;

    const float* Wp = w2_0 + (size_t)idx1 * (CIN_ * 32);
    acc = 0.f;
    #pragma unroll
    for (int i = 0; i < 64; ++i) { int ii = half * 64 + i; acc += xr[ii] * Wp[ii * 32 + o]; }
    acc += __shfl_xor(acc, 32);
    y = lrelu(acc + b2_0[idx1 * 32 + o]);
    Wp = w2_1 + (size_t)idx1 * 1024;
    acc = 0.f;
    #pragma unroll
    for (int i = 0; i < 32; ++i) acc += __shfl(y, i) * Wp[i * 32 + o];
    y2 = lrelu(acc + b2_1[idx1 * 32 + o]);
    Wp = w2_2 + (size_t)idx1 * 1024;
    acc = 0.f;
    #pragma unroll
    for (int i = 0; i < 32; ++i) acc += __shfl(y2, i) * Wp[i * 32 + o];
    float y3 = acc + b2_2[idx1 * 32 + o];

    bv = y3; bi = o;
    #pragma unroll
    for (int d = 1; d < 32; d <<= 1) {
        float ov = __shfl_xor(bv, d); int oi = __shfl_xor(bi, d);
        if (ov > bv || (ov == bv && oi < bi)) { bv = ov; bi = oi; }
    }
    const int inds2  = bi;
    const int inds12 = inds1 * 16 + inds2 - 8;
    const int clip12 = min(max(inds12, 0), 255);
    const int idx12  = clip12 + 256 * h;

    Wp = w3_0 + (size_t)idx12 * (CIN_ * 32);
    acc = 0.f;
    #pragma unroll
    for (int i = 0; i < 64; ++i) { int ii = half * 64 + i; acc += xr[ii] * Wp[ii * 32 + o]; }
    acc += __shfl_xor(acc, 32);
    y = lrelu(acc + b3_0[idx12 * 32 + o]);
    Wp = w3_1 + (size_t)idx12 * 1024;
    acc = 0.f;
    #pragma unroll
    for (int i = 0; i < 32; ++i) acc += __shfl(y, i) * Wp[i * 32 + o];
    y2 = lrelu(acc + b3_1[idx12 * 32 + o]);
    Wp = w3_2 + (size_t)idx12 * 1024;
    acc = 0.f;
    #pragma unroll
    for (int i = 0; i < 32; ++i) acc += __shfl(y2, i) * Wp[i * 32 + o];
    y3 = acc + b3_2[idx12 * 32 + o];

    bv = y3; bi = o;
    #pragma unroll
    for (int d = 1; d < 32; d <<= 1) {
        float ov = __shfl_xor(bv, d); int oi = __shfl_xor(bi, d);
        if (ov > bv || (ov == bv && oi < bi)) { bv = ov; bi = oi; }
    }
    int inds123 = inds12 * 16 + bi - 8;
    inds123 = min(max(inds123, 0), 4095);
    if (lane == 0) out[h * WW + w0 + wave] = inds123;
}

extern "C" void kernel_launch(void* const* d_in, const int* in_sizes, int n_in,
                              void* d_out, int out_size, void* d_ws, size_t ws_size,
                              hipStream_t stream)
{
    const float* x_in = (const float*)d_in[0];
    const float* w1_0 = (const float*)d_in[1];
    const float* b1_0 = (const float*)d_in[2];
    const float* w1_1 = (const float*)d_in[3];
    const float* b1_1 = (const float*)d_in[4];
    const float* w1_2 = (const float*)d_in[5];
    const float* b1_2 = (const float*)d_in[6];
    const float* w2_0 = (const float*)d_in[7];
    const float* b2_0 = (const float*)d_in[8];
    const float* w2_1 = (const float*)d_in[9];
    const float* b2_1 = (const float*)d_in[10];
    const float* w2_2 = (const float*)d_in[11];
    const float* b2_2 = (const float*)d_in[12];
    const float* w3_0 = (const float*)d_in[13];
    const float* b3_0 = (const float*)d_in[14];
    const float* w3_1 = (const float*)d_in[15];
    const float* b3_1 = (const float*)d_in[16];
    const float* w3_2 = (const float*)d_in[17];
    const float* b3_2 = (const float*)d_in[18];
    int* out = (int*)d_out;

    // ws layout (bytes)
    char* ws = (char*)d_ws;
    int*   inds1_ws  = (int*)(ws + 0);                 // HW ints
    int*   inds12_ws = (int*)(ws + 143360);            // HW ints
    int*   sorted2   = (int*)(ws + 286720);            // HW ints
    int*   sorted3   = (int*)(ws + 430080);            // HW ints
    int*   qc2       = (int*)(ws + 573440);
    int*   qc3       = (int*)(ws + 573444);
    int4*  queue2    = (int4*)(ws + 573456);           // HW entries max
    int4*  queue3    = (int4*)(ws + 1146896);          // HW entries max
    float* xT_ws     = (float*)(ws + 1720336);         // HW*128 floats
    const size_t NEED = 1720336 + (size_t)HW_ * CIN_ * 4;   // ~20.07 MB

    if (ws_size >= NEED) {
        k1_stage1<<<HH * 4, 512, 0, stream>>>(
            x_in, w1_0, b1_0, w1_1, b1_1, w1_2, b1_2,
            inds1_ws, xT_ws, qc2, qc3);
        sorter<16><<<HH, 512, 0, stream>>>(inds1_ws, 15, sorted2, queue2, qc2);
        qk_compute<2><<<1024, 512, 0, stream>>>(
            xT_ws, sorted2, queue2, qc2,
            w2_0, b2_0, w2_1, b2_1, w2_2, b2_2, nullptr, inds12_ws);
        sorter<256><<<HH, 512, 0, stream>>>(inds12_ws, 255, sorted3, queue3, qc3);
        qk_compute<3><<<1024, 512, 0, stream>>>(
            xT_ws, sorted3, queue3, qc3,
            w3_0, b3_0, w3_1, b3_1, w3_2, b3_2, inds12_ws, out);
    } else {
        reg3_fused<<<HH * 40, 512, 0, stream>>>(
            x_in, w1_0, b1_0, w1_1, b1_1, w1_2, b1_2,
            w2_0, b2_0, w2_1, b2_1, w2_2, b2_2,
            w3_0, b3_0, w3_1, b3_1, w3_2, b3_2, out);
    }
}

// Round 7
// 222.429 us; speedup vs baseline: 2.9676x; 1.2649x over previous
//
#include <hip/hip_runtime.h>

#define HH   112
#define WW   320
#define CIN_ 128
#define HW_  (HH * WW)        // 35840
#define CHUNK 32              // max pixels per queue item

__device__ __forceinline__ float lrelu(float v) {
    return v >= 0.f ? v : 0.01f * v;
}

// ============================================================================
// K1: stage 1 (per-line grouped 1x1 chain) -> inds1 + xT dump; zeroes qcounts.
// 4 blocks per quarter-line, 5 tiles of 16 pixels, 2 pixels per wave
// INTERLEAVED (independent FMA chains hide dep latency; per-output
// accumulation order is bit-identical to the proven kernel).
// ============================================================================
__global__ __launch_bounds__(512, 2)
void k1_stage1(const float* __restrict__ x_in,
               const float* __restrict__ w1_0, const float* __restrict__ b1_0,
               const float* __restrict__ w1_1, const float* __restrict__ b1_1,
               const float* __restrict__ w1_2, const float* __restrict__ b1_2,
               int* __restrict__ inds1_out, float* __restrict__ xT_out,
               int* __restrict__ qc2, int* __restrict__ qc3)
{
    __shared__ float w1s0[32][CIN_ + 1];   // stride 129: scalar reads conflict-free
    __shared__ float w1s1[32][33];
    __shared__ float w1s2[16][33];
    __shared__ float b1s[80];
    __shared__ float xT[16][132];          // stride 132: float4-aligned rows

    const int h   = blockIdx.x >> 2;
    const int q   = blockIdx.x & 3;
    const int tid = threadIdx.x;
    const int base = h * WW;

    if (blockIdx.x == 0 && tid == 0) { *qc2 = 0; *qc3 = 0; }

    for (int n = tid; n < 32 * CIN_; n += 512)
        w1s0[n >> 7][n & 127] = w1_0[h * (32 * CIN_) + n];
    for (int n = tid; n < 32 * 32; n += 512)
        w1s1[n >> 5][n & 31] = w1_1[h * 1024 + n];
    if (tid < 16 * 32)
        w1s2[tid >> 5][tid & 31] = w1_2[h * 512 + tid];
    if      (tid < 32) b1s[tid] = b1_0[h * 32 + tid];
    else if (tid < 64) b1s[tid] = b1_1[h * 32 + (tid - 32)];
    else if (tid < 80) b1s[tid] = b1_2[h * 16 + (tid - 64)];
    __syncthreads();

    const int wave = tid >> 6;
    const int lane = tid & 63;
    const int o    = lane & 31;
    const int half = lane >> 5;
    const int o16  = lane & 15;

    for (int t = 0; t < 5; ++t) {
        const int w0 = q * 80 + t * 16;
        for (int n = tid; n < 16 * CIN_; n += 512) {
            int ww = n & 15, c = n >> 4;
            xT[ww][c] = x_in[c * HW_ + base + w0 + ww];
        }
        __syncthreads();
        for (int n = tid; n < 16 * CIN_; n += 512) {
            int pix = n >> 7, c = n & 127;
            xT_out[(size_t)(base + w0 + pix) * CIN_ + c] = xT[pix][c];
        }
        const float* xA = &xT[wave][0];
        const float* xB = &xT[wave + 8][0];

        // ---- matvec1 128->32 (weights shared across A/B; order exact) ----
        float aA = 0.f, aB = 0.f;
        #pragma unroll
        for (int i = 0; i < 64; i += 4) {
            const int ii = half * 64 + i;
            const float w0v = w1s0[o][ii];
            const float w1v = w1s0[o][ii + 1];
            const float w2v = w1s0[o][ii + 2];
            const float w3v = w1s0[o][ii + 3];
            const float4 a4 = *reinterpret_cast<const float4*>(&xA[ii]);
            const float4 b4 = *reinterpret_cast<const float4*>(&xB[ii]);
            aA += a4.x * w0v;  aB += b4.x * w0v;
            aA += a4.y * w1v;  aB += b4.y * w1v;
            aA += a4.z * w2v;  aB += b4.z * w2v;
            aA += a4.w * w3v;  aB += b4.w * w3v;
        }
        aA += __shfl_xor(aA, 32);
        aB += __shfl_xor(aB, 32);
        float yA = lrelu(aA + b1s[o]);
        float yB = lrelu(aB + b1s[o]);

        // ---- matvec2 32->32 ----
        aA = 0.f; aB = 0.f;
        #pragma unroll
        for (int i = 0; i < 32; ++i) {
            const float wv = w1s1[o][i];
            aA += __shfl(yA, i) * wv;
            aB += __shfl(yB, i) * wv;
        }
        float y2A = lrelu(aA + b1s[32 + o]);
        float y2B = lrelu(aB + b1s[32 + o]);

        // ---- matvec3 32->16 ----
        aA = 0.f; aB = 0.f;
        #pragma unroll
        for (int i = 0; i < 32; ++i) {
            const float wv = w1s2[o16][i];
            aA += __shfl(y2A, i) * wv;
            aB += __shfl(y2B, i) * wv;
        }
        const float t1A = aA + b1s[64 + o16];
        const float t1B = aB + b1s[64 + o16];

        // ---- argmax16, first-index tie-break, interleaved ----
        float bvA = t1A, bvB = t1B;
        int   biA = o16, biB = o16;
        #pragma unroll
        for (int d = 1; d < 16; d <<= 1) {
            float ovA = __shfl_xor(bvA, d), ovB = __shfl_xor(bvB, d);
            int   oiA = __shfl_xor(biA, d), oiB = __shfl_xor(biB, d);
            if (ovA > bvA || (ovA == bvA && oiA < biA)) { bvA = ovA; biA = oiA; }
            if (ovB > bvB || (ovB == bvB && oiB < biB)) { bvB = ovB; biB = oiB; }
        }
        if (lane == 0) {
            inds1_out[base + w0 + wave]     = biA;
            inds1_out[base + w0 + wave + 8] = biB;
        }
        __syncthreads();
    }
}

// ============================================================================
// Sorter: one block per line. Bucket-sort pixels by (clipped) routing index,
// emit <=CHUNK-pixel work items to the global queue. Item order is
// nondeterministic (atomics) but the item set and all outputs are not.
// ============================================================================
template <int BINS>
__global__ void sorter(const int* __restrict__ inds_in, int clipmax,
                       int* __restrict__ sorted, int4* __restrict__ queue,
                       int* __restrict__ qcount)
{
    __shared__ int cnt[BINS];
    __shared__ int scan[BINS];
    __shared__ int rank[BINS];

    const int h = blockIdx.x, tid = threadIdx.x, base = h * WW;
    if (tid < BINS) { cnt[tid] = 0; rank[tid] = 0; }
    __syncthreads();

    int c = -1;
    if (tid < WW) {
        c = inds_in[base + tid];
        c = min(max(c, 0), clipmax);
        atomicAdd(&cnt[c], 1);
    }
    __syncthreads();
    if (tid < BINS) scan[tid] = cnt[tid];
    __syncthreads();
    for (int s = 1; s < BINS; s <<= 1) {
        int v = 0;
        if (tid >= s && tid < BINS) v = scan[tid - s];
        __syncthreads();
        if (tid < BINS) scan[tid] += v;
        __syncthreads();
    }
    if (tid < WW) {
        int pos = (scan[c] - cnt[c]) + atomicAdd(&rank[c], 1);
        sorted[base + pos] = base + tid;          // absolute pixel id
    }
    if (tid < BINS && cnt[tid] > 0) {
        int offc = scan[tid] - cnt[tid];
        for (int s0 = 0; s0 < cnt[tid]; s0 += CHUNK) {
            int qi = atomicAdd(qcount, 1);
            queue[qi] = make_int4(h, tid, base + offc + s0,
                                  min(CHUNK, cnt[tid] - s0));
        }
    }
}

// ============================================================================
// Queue-driven CondMul chain. 256 threads (4 waves), 4 blocks/CU, grid-stride
// over items. Per item: weight chain -> LDS once; 2 pixels per wave
// INTERLEAVED (independent chains; per-pixel FP order bit-identical).
// ============================================================================
template <int STAGE>
__global__ __launch_bounds__(256, 4)
void qk_compute(const float* __restrict__ xT_in, const int* __restrict__ sorted,
                const int4* __restrict__ queue, const int* __restrict__ qcount,
                const float* __restrict__ W0, const float* __restrict__ Bb0,
                const float* __restrict__ W1, const float* __restrict__ Bb1,
                const float* __restrict__ W2, const float* __restrict__ Bb2,
                const int* __restrict__ inds12_in, int* __restrict__ result)
{
    __shared__ float ws0[CIN_ * 32];
    __shared__ float ws1[32 * 32];
    __shared__ float ws2[32 * 32];
    __shared__ float bs[96];
    __shared__ float xbuf[8][CIN_];

    const int tid  = threadIdx.x;
    const int wave = tid >> 6;
    const int lane = tid & 63;
    const int o    = lane & 31;
    const int half = lane >> 5;

    const int qn = *qcount;
    for (int qi = blockIdx.x; qi < qn; qi += gridDim.x) {
        const int4 it4   = queue[qi];
        const int  c     = it4.y;
        const int  start = it4.z;
        const int  n     = it4.w;
        const int  key   = (STAGE == 2) ? (it4.x * 16 + c) : (it4.x * 256 + c);

        __syncthreads();                          // protect LDS reuse
        for (int i = tid; i < 1024; i += 256)
            ((float4*)ws0)[i] = ((const float4*)(W0 + (size_t)key * 4096))[i];
        if (tid < 256) {
            ((float4*)ws1)[tid] = ((const float4*)(W1 + (size_t)key * 1024))[tid];
            ((float4*)ws2)[tid] = ((const float4*)(W2 + (size_t)key * 1024))[tid];
        }
        if      (tid < 32) bs[tid] = Bb0[(size_t)key * 32 + tid];
        else if (tid < 64) bs[tid] = Bb1[(size_t)key * 32 + (tid - 32)];
        else if (tid < 96) bs[tid] = Bb2[(size_t)key * 32 + (tid - 64)];
        __syncthreads();

        const int sA = wave * 2, sB = wave * 2 + 1;
        for (int t0 = wave * 2; t0 < n; t0 += 8) {
            const bool vB  = (t0 + 1) < n;
            const int pixA = sorted[start + t0];
            const int pixB = vB ? sorted[start + t0 + 1] : pixA;
            xbuf[sA][lane]      = xT_in[(size_t)pixA * CIN_ + lane];
            xbuf[sA][64 + lane] = xT_in[(size_t)pixA * CIN_ + 64 + lane];
            xbuf[sB][lane]      = xT_in[(size_t)pixB * CIN_ + lane];
            xbuf[sB][64 + lane] = xT_in[(size_t)pixB * CIN_ + 64 + lane];
            asm volatile("s_waitcnt vmcnt(0) lgkmcnt(0)" ::: "memory");
            const float* xA = &xbuf[sA][0];
            const float* xB = &xbuf[sB][0];

            // ---- matvec1 128->32 (weights shared across A/B) ----
            float aA = 0.f, aB = 0.f;
            #pragma unroll
            for (int i = 0; i < 64; i += 4) {
                const int ii = half * 64 + i;
                const float w0v = ws0[(ii + 0) * 32 + o];
                const float w1v = ws0[(ii + 1) * 32 + o];
                const float w2v = ws0[(ii + 2) * 32 + o];
                const float w3v = ws0[(ii + 3) * 32 + o];
                const float4 a4 = *reinterpret_cast<const float4*>(&xA[ii]);
                const float4 b4 = *reinterpret_cast<const float4*>(&xB[ii]);
                aA += a4.x * w0v;  aB += b4.x * w0v;
                aA += a4.y * w1v;  aB += b4.y * w1v;
                aA += a4.z * w2v;  aB += b4.z * w2v;
                aA += a4.w * w3v;  aB += b4.w * w3v;
            }
            aA += __shfl_xor(aA, 32);
            aB += __shfl_xor(aB, 32);
            float yA = lrelu(aA + bs[o]);
            float yB = lrelu(aB + bs[o]);

            // ---- matvec2 32->32 ----
            aA = 0.f; aB = 0.f;
            #pragma unroll
            for (int i = 0; i < 32; ++i) {
                const float wv = ws1[i * 32 + o];
                aA += __shfl(yA, i) * wv;
                aB += __shfl(yB, i) * wv;
            }
            float y2A = lrelu(aA + bs[32 + o]);
            float y2B = lrelu(aB + bs[32 + o]);

            // ---- matvec3 32->32 ----
            aA = 0.f; aB = 0.f;
            #pragma unroll
            for (int i = 0; i < 32; ++i) {
                const float wv = ws2[i * 32 + o];
                aA += __shfl(y2A, i) * wv;
                aB += __shfl(y2B, i) * wv;
            }
            const float y3A = aA + bs[64 + o];
            const float y3B = aB + bs[64 + o];

            // ---- argmax32, first-index tie-break, interleaved ----
            float bvA = y3A, bvB = y3B;
            int   biA = o,   biB = o;
            #pragma unroll
            for (int d = 1; d < 32; d <<= 1) {
                float ovA = __shfl_xor(bvA, d), ovB = __shfl_xor(bvB, d);
                int   oiA = __shfl_xor(biA, d), oiB = __shfl_xor(biB, d);
                if (ovA > bvA || (ovA == bvA && oiA < biA)) { bvA = ovA; biA = oiA; }
                if (ovB > bvB || (ovB == bvB && oiB < biB)) { bvB = ovB; biB = oiB; }
            }
            if (lane == 0) {
                if (STAGE == 2) {
                    result[pixA] = c * 16 + biA - 8;            // unclipped
                    if (vB) result[pixB] = c * 16 + biB - 8;
                } else {
                    int vA12 = inds12_in[pixA];
                    result[pixA] = min(max(vA12 * 16 + biA - 8, 0), 4095);
                    if (vB) {
                        int vB12 = inds12_in[pixB];
                        result[pixB] = min(max(vB12 * 16 + biB - 8, 0), 4095);
                    }
                }
            }
        }
    }
}

// ============================================================================
// Fallback: proven monolithic kernel (only if d_ws too small — not expected).
// ============================================================================
__global__ __launch_bounds__(512, 4)
void reg3_fused(const float* __restrict__ x_in,
                const float* __restrict__ w1_0, const float* __restrict__ b1_0,
                const float* __restrict__ w1_1, const float* __restrict__ b1_1,
                const float* __restrict__ w1_2, const float* __restrict__ b1_2,
                const float* __restrict__ w2_0, const float* __restrict__ b2_0,
                const float* __restrict__ w2_1, const float* __restrict__ b2_1,
                const float* __restrict__ w2_2, const float* __restrict__ b2_2,
                const float* __restrict__ w3_0, const float* __restrict__ b3_0,
                const float* __restrict__ w3_1, const float* __restrict__ b3_1,
                const float* __restrict__ w3_2, const float* __restrict__ b3_2,
                int* __restrict__ out)
{
    __shared__ float xT[8][CIN_ + 1];
    __shared__ float w1s0[32][CIN_ + 1];
    __shared__ float w1s1[32][33];
    __shared__ float w1s2[16][33];
    __shared__ float b1s[80];

    const int h   = blockIdx.x / 40;
    const int w0  = (blockIdx.x % 40) * 8;
    const int tid = threadIdx.x;

    for (int n = tid; n < 8 * CIN_; n += 512) {
        int ww = n & 7, c = n >> 3;
        xT[ww][c] = x_in[c * HW_ + h * WW + w0 + ww];
    }
    for (int n = tid; n < 32 * CIN_; n += 512)
        w1s0[n >> 7][n & 127] = w1_0[h * (32 * CIN_) + n];
    for (int n = tid; n < 32 * 32; n += 512)
        w1s1[n >> 5][n & 31] = w1_1[h * 1024 + n];
    if (tid < 16 * 32)
        w1s2[tid >> 5][tid & 31] = w1_2[h * 512 + tid];
    if      (tid < 32) b1s[tid] = b1_0[h * 32 + tid];
    else if (tid < 64) b1s[tid] = b1_1[h * 32 + (tid - 32)];
    else if (tid < 80) b1s[tid] = b1_2[h * 16 + (tid - 64)];
    __syncthreads();

    const int wave = tid >> 6, lane = tid & 63;
    const int o = lane & 31, half = lane >> 5, o16 = lane & 15;
    const float* xr = &xT[wave][0];

    float acc = 0.f;
    #pragma unroll
    for (int i = 0; i < 64; ++i) { int ii = half * 64 + i; acc += xr[ii] * w1s0[o][ii]; }
    acc += __shfl_xor(acc, 32);
    float y = lrelu(acc + b1s[o]);
    acc = 0.f;
    #pragma unroll
    for (int i = 0; i < 32; ++i) acc += __shfl(y, i) * w1s1[o][i];
    float y2 = lrelu(acc + b1s[32 + o]);
    acc = 0.f;
    #pragma unroll
    for (int i = 0; i < 32; ++i) acc += __shfl(y2, i) * w1s2[o16][i];
    float t1 = acc + b1s[64 + o16];

    float bv = t1; int bi = o16;
    #pragma unroll
    for (int d = 1; d < 16; d <<= 1) {
        float ov = __shfl_xor(bv, d); int oi = __shfl_xor(bi, d);
        if (ov > bv || (ov == bv && oi < bi)) { bv = ov; bi = oi; }
    }
    const int inds1 = bi;
    const int idx1  = inds1 + 16 * h;

    const float* Wp = w2_0 + (size_t)idx1 * (CIN_ * 32);
    acc = 0.f;
    #pragma unroll
    for (int i = 0; i < 64; ++i) { int ii = half * 64 + i; acc += xr[ii] * Wp[ii * 32 + o]; }
    acc += __shfl_xor(acc, 32);
    y = lrelu(acc + b2_0[idx1 * 32 + o]);
    Wp = w2_1 + (size_t)idx1 * 1024;
    acc = 0.f;
    #pragma unroll
    for (int i = 0; i < 32; ++i) acc += __shfl(y, i) * Wp[i * 32 + o];
    y2 = lrelu(acc + b2_1[idx1 * 32 + o]);
    Wp = w2_2 + (size_t)idx1 * 1024;
    acc = 0.f;
    #pragma unroll
    for (int i = 0; i < 32; ++i) acc += __shfl(y2, i) * Wp[i * 32 + o];
    float y3 = acc + b2_2[idx1 * 32 + o];

    bv = y3; bi = o;
    #pragma unroll
    for (int d = 1; d < 32; d <<= 1) {
        float ov = __shfl_xor(bv, d); int oi = __shfl_xor(bi, d);
        if (ov > bv || (ov == bv && oi < bi)) { bv = ov; bi = oi; }
    }
    const int inds2  = bi;
    const int inds12 = inds1 * 16 + inds2 - 8;
    const int clip12 = min(max(inds12, 0), 255);
    const int idx12  = clip12 + 256 * h;

    Wp = w3_0 + (size_t)idx12 * (CIN_ * 32);
    acc = 0.f;
    #pragma unroll
    for (int i = 0; i < 64; ++i) { int ii = half * 64 + i; acc += xr[ii] * Wp[ii * 32 + o]; }
    acc += __shfl_xor(acc, 32);
    y = lrelu(acc + b3_0[idx12 * 32 + o]);
    Wp = w3_1 + (size_t)idx12 * 1024;
    acc = 0.f;
    #pragma unroll
    for (int i = 0; i < 32; ++i) acc += __shfl(y, i) * Wp[i * 32 + o];
    y2 = lrelu(acc + b3_1[idx12 * 32 + o]);
    Wp = w3_2 + (size_t)idx12 * 1024;
    acc = 0.f;
    #pragma unroll
    for (int i = 0; i < 32; ++i) acc += __shfl(y2, i) * Wp[i * 32 + o];
    y3 = acc + b3_2[idx12 * 32 + o];

    bv = y3; bi = o;
    #pragma unroll
    for (int d = 1; d < 32; d <<= 1) {
        float ov = __shfl_xor(bv, d); int oi = __shfl_xor(bi, d);
        if (ov > bv || (ov == bv && oi < bi)) { bv = ov; bi = oi; }
    }
    int inds123 = inds12 * 16 + bi - 8;
    inds123 = min(max(inds123, 0), 4095);
    if (lane == 0) out[h * WW + w0 + wave] = inds123;
}

extern "C" void kernel_launch(void* const* d_in, const int* in_sizes, int n_in,
                              void* d_out, int out_size, void* d_ws, size_t ws_size,
                              hipStream_t stream)
{
    const float* x_in = (const float*)d_in[0];
    const float* w1_0 = (const float*)d_in[1];
    const float* b1_0 = (const float*)d_in[2];
    const float* w1_1 = (const float*)d_in[3];
    const float* b1_1 = (const float*)d_in[4];
    const float* w1_2 = (const float*)d_in[5];
    const float* b1_2 = (const float*)d_in[6];
    const float* w2_0 = (const float*)d_in[7];
    const float* b2_0 = (const float*)d_in[8];
    const float* w2_1 = (const float*)d_in[9];
    const float* b2_1 = (const float*)d_in[10];
    const float* w2_2 = (const float*)d_in[11];
    const float* b2_2 = (const float*)d_in[12];
    const float* w3_0 = (const float*)d_in[13];
    const float* b3_0 = (const float*)d_in[14];
    const float* w3_1 = (const float*)d_in[15];
    const float* b3_1 = (const float*)d_in[16];
    const float* w3_2 = (const float*)d_in[17];
    const float* b3_2 = (const float*)d_in[18];
    int* out = (int*)d_out;

    // ws layout (bytes)
    char* ws = (char*)d_ws;
    int*   inds1_ws  = (int*)(ws + 0);                 // HW ints
    int*   inds12_ws = (int*)(ws + 143360);            // HW ints
    int*   sorted2   = (int*)(ws + 286720);            // HW ints
    int*   sorted3   = (int*)(ws + 430080);            // HW ints
    int*   qc2       = (int*)(ws + 573440);
    int*   qc3       = (int*)(ws + 573444);
    int4*  queue2    = (int4*)(ws + 573456);           // HW entries max
    int4*  queue3    = (int4*)(ws + 1146896);          // HW entries max
    float* xT_ws     = (float*)(ws + 1720336);         // HW*128 floats
    const size_t NEED = 1720336 + (size_t)HW_ * CIN_ * 4;   // ~20.07 MB

    if (ws_size >= NEED) {
        k1_stage1<<<HH * 4, 512, 0, stream>>>(
            x_in, w1_0, b1_0, w1_1, b1_1, w1_2, b1_2,
            inds1_ws, xT_ws, qc2, qc3);
        sorter<16><<<HH, 512, 0, stream>>>(inds1_ws, 15, sorted2, queue2, qc2);
        qk_compute<2><<<2048, 256, 0, stream>>>(
            xT_ws, sorted2, queue2, qc2,
            w2_0, b2_0, w2_1, b2_1, w2_2, b2_2, nullptr, inds12_ws);
        sorter<256><<<HH, 512, 0, stream>>>(inds12_ws, 255, sorted3, queue3, qc3);
        qk_compute<3><<<2048, 256, 0, stream>>>(
            xT_ws, sorted3, queue3, qc3,
            w3_0, b3_0, w3_1, b3_1, w3_2, b3_2, inds12_ws, out);
    } else {
        reg3_fused<<<HH * 40, 512, 0, stream>>>(
            x_in, w1_0, b1_0, w1_1, b1_1, w1_2, b1_2,
            w2_0, b2_0, w2_1, b2_1, w2_2, b2_2,
            w3_0, b3_0, w3_1, b3_1, w3_2, b3_2, out);
    }
}